// Round 8
// baseline (348.679 us; speedup 1.0000x reference)
//
#include <hip/hip_runtime.h>

#define NDIM 128
#define BKT_SHIFT 9            // 512 nodes per bucket
#define BKT_NODES 512
#define BKT_CAP   12288        // edges capacity per bucket (mean ~8163)
#define PART_CHUNK 4096        // edges per block in partition kernel
#define APAD 136               // A-tile row stride in u16 (272 B: 16B-aligned, banks spread)

typedef unsigned short u16;
typedef unsigned int u32;
typedef __attribute__((ext_vector_type(8))) short bf16x8;
typedef __attribute__((ext_vector_type(4))) float f32x4;

__device__ inline u16 f2bf(float f) {
    u32 u = __float_as_uint(f);
    u += 0x7fffu + ((u >> 16) & 1u);   // RNE
    return (u16)(u >> 16);
}
__device__ inline float bf2f(u16 h) { return __uint_as_float((u32)h << 16); }

// ---------------- bucketed CSR build (unchanged — working) ----------------

__global__ __launch_bounds__(256) void partition_kernel(
    const int* __restrict__ ei, int E,
    int* __restrict__ gcur, u32* __restrict__ ebuf) {
    __shared__ int hcnt[256];
    __shared__ int hbase[256];
    const int tid = threadIdx.x;
    const int base = blockIdx.x * PART_CHUNK;
    hcnt[tid] = 0;
    __syncthreads();

    u32 val[16];
    int bkt[16];
    #pragma unroll
    for (int k = 0; k < 16; ++k) {
        int e = base + k * 256 + tid;
        bkt[k] = -1;
        if (e < E) {
            int src = ei[e];
            int dst = ei[(size_t)E + e];
            int b = dst >> BKT_SHIFT;
            bkt[k] = b;
            val[k] = ((u32)src << BKT_SHIFT) | (u32)(dst & (BKT_NODES - 1));
            atomicAdd(&hcnt[b], 1);
        }
    }
    __syncthreads();
    {
        int c = hcnt[tid];
        if (c > 0) hbase[tid] = atomicAdd(&gcur[tid], c);
        hcnt[tid] = 0;   // reuse as rank counter
    }
    __syncthreads();
    #pragma unroll
    for (int k = 0; k < 16; ++k) {
        if (bkt[k] >= 0) {
            int b = bkt[k];
            int r = atomicAdd(&hcnt[b], 1);
            int off = hbase[b] + r;
            if (off < BKT_CAP)
                ebuf[(size_t)b * BKT_CAP + off] = val[k];
        }
    }
}

__global__ __launch_bounds__(256) void bucket_csr_kernel(
    const int* __restrict__ gcur, const u32* __restrict__ ebuf,
    int* __restrict__ row_beg, int* __restrict__ degN,
    int* __restrict__ col, int n) {
    __shared__ int deg_l[BKT_NODES];
    __shared__ int pre_l[BKT_NODES];
    __shared__ int cur_l[BKT_NODES];
    __shared__ int wsum[4];
    const int tid = threadIdx.x;
    const int lane = tid & 63, wid = tid >> 6;
    const int b = blockIdx.x;
    const int node0 = b << BKT_SHIFT;
    int cnt = gcur[b];
    if (cnt > BKT_CAP) cnt = BKT_CAP;
    const size_t ebase = (size_t)b * BKT_CAP;

    deg_l[tid] = 0; deg_l[tid + 256] = 0;
    cur_l[tid] = 0; cur_l[tid + 256] = 0;
    __syncthreads();

    for (int i = tid; i < cnt; i += 256)
        atomicAdd(&deg_l[ebuf[ebase + i] & (BKT_NODES - 1)], 1);
    __syncthreads();

    int v0 = deg_l[2 * tid], v1 = deg_l[2 * tid + 1];
    int s = v0 + v1, inc = s;
    #pragma unroll
    for (int d = 1; d < 64; d <<= 1) {
        int t = __shfl_up(inc, d, 64);
        if (lane >= d) inc += t;
    }
    if (lane == 63) wsum[wid] = inc;
    __syncthreads();
    int woff = 0;
    for (int w = 0; w < wid; ++w) woff += wsum[w];
    int ex = woff + (inc - s);
    pre_l[2 * tid] = ex;
    pre_l[2 * tid + 1] = ex + v0;
    __syncthreads();

    #pragma unroll
    for (int p = 0; p < 2; ++p) {
        int idx = tid + p * 256;
        int node = node0 + idx;
        if (node < n) {
            row_beg[node] = (int)ebase + pre_l[idx];
            degN[node]    = deg_l[idx];
        }
    }

    for (int i = tid; i < cnt; i += 256) {
        u32 v = ebuf[ebase + i];
        int d = v & (BKT_NODES - 1);
        int r = atomicAdd(&cur_l[d], 1);
        col[ebase + pre_l[d] + r] = (int)(v >> BKT_SHIFT);
    }
}

// ---------------- weight prep: Wt[o][k] split bf16 hi/lo, k = [w_l | w_r] ----------------

__global__ void build_wt_kernel(const float* __restrict__ wl,
                                const float* __restrict__ wr,
                                u16* __restrict__ wth, u16* __restrict__ wtl) {
    int idx = blockIdx.x * blockDim.x + threadIdx.x;
    if (idx >= 128 * 256) return;
    int o = idx >> 8, k = idx & 255;
    float v = (k < 128) ? wl[o * 128 + k] : wr[o * 128 + (k - 128)];
    u16 hi = f2bf(v);
    wth[idx] = hi;
    wtl[idx] = f2bf(v - bf2f(hi));
}

// ---------------- fp32 -> bf16(hi) table ----------------

__global__ __launch_bounds__(256) void to_bf16_kernel(
    const float* __restrict__ in, u16* __restrict__ out, int n4) {
    int stride = gridDim.x * blockDim.x;
    for (int i = blockIdx.x * blockDim.x + threadIdx.x; i < n4; i += stride) {
        float4 v = *(const float4*)&in[(size_t)i * 4];
        ushort4 o;
        o.x = f2bf(v.x); o.y = f2bf(v.y); o.z = f2bf(v.z); o.w = f2bf(v.w);
        *(ushort4*)&out[(size_t)i * 4] = o;
    }
}

// ---------------- fused: mean-aggregate (16 nodes) + MFMA GEMM tile ----------------
// Phase 1 (gather): identical structure to the proven aggregate_bf16_kernel —
//   16 lanes/node, fp32 accumulate, 1 uint4 (8 bf16 dims) per neighbor per lane.
//   Result converted to bf16 hi/lo into a padded LDS A-tile [16][256].
// Phase 2 (MFMA): 4 waves, each 16 rows x 32 cols (nt=2). A k<128 from LDS
//   (hi+lo split, 3 MFMA); k>=128 self-side direct from global (hi only +
//   W-lo term, 2 MFMA). D: col=lane&15, row=(lane>>4)*4+reg (m89/m91 layout).
// Removes the agg hi/lo round-trip (102 MB/layer) and one dispatch per layer.

__device__ inline void accum8(float acc[8], uint4 u) {
    const u32* p = (const u32*)&u;
    #pragma unroll
    for (int q = 0; q < 4; ++q) {
        u32 w = p[q];
        acc[2 * q]     += __uint_as_float(w << 16);
        acc[2 * q + 1] += __uint_as_float(w & 0xffff0000u);
    }
}

__global__ __launch_bounds__(256) void fused_agg_gemm_kernel(
    const u16* __restrict__ feat,       // bf16 node features (gather + self side)
    const int* __restrict__ row_beg, const int* __restrict__ degN,
    const int* __restrict__ col,
    const u16* __restrict__ wth, const u16* __restrict__ wtl,
    const float* __restrict__ bias,
    float* __restrict__ outF, u16* __restrict__ outH,
    int n, int do_relu) {
    __shared__ u16 Ah[16][APAD];
    __shared__ u16 Al[16][APAD];

    const int tid  = threadIdx.x;
    const int node0 = blockIdx.x * 16;

    // ---- phase 1: gather ----
    {
        const int nl = tid >> 4;        // node-local 0..15
        const int l  = tid & 15;        // dim group: dims [8l, 8l+8)
        const int node = node0 + nl;
        float acc[8] = {0.f, 0.f, 0.f, 0.f, 0.f, 0.f, 0.f, 0.f};
        if (node < n) {
            int beg = row_beg[node];
            int dg  = degN[node];
            int end = beg + dg;
            int j = beg;
            for (; j + 4 <= end; j += 4) {
                int s0 = col[j], s1 = col[j + 1], s2 = col[j + 2], s3 = col[j + 3];
                uint4 u0 = *(const uint4*)&feat[(size_t)s0 * NDIM + l * 8];
                uint4 u1 = *(const uint4*)&feat[(size_t)s1 * NDIM + l * 8];
                uint4 u2 = *(const uint4*)&feat[(size_t)s2 * NDIM + l * 8];
                uint4 u3 = *(const uint4*)&feat[(size_t)s3 * NDIM + l * 8];
                accum8(acc, u0); accum8(acc, u1); accum8(acc, u2); accum8(acc, u3);
            }
            for (; j < end; ++j) {
                uint4 u = *(const uint4*)&feat[(size_t)col[j] * NDIM + l * 8];
                accum8(acc, u);
            }
            float inv = (dg > 0) ? 1.0f / (float)dg : 0.f;
            #pragma unroll
            for (int q = 0; q < 8; ++q) acc[q] *= inv;
        }
        u32 hw[4], lw[4];
        #pragma unroll
        for (int q = 0; q < 4; ++q) {
            u16 h0 = f2bf(acc[2 * q]);
            u16 h1 = f2bf(acc[2 * q + 1]);
            u16 l0 = f2bf(acc[2 * q]     - bf2f(h0));
            u16 l1 = f2bf(acc[2 * q + 1] - bf2f(h1));
            hw[q] = (u32)h0 | ((u32)h1 << 16);
            lw[q] = (u32)l0 | ((u32)l1 << 16);
        }
        *(uint4*)&Ah[nl][l * 8] = make_uint4(hw[0], hw[1], hw[2], hw[3]);
        *(uint4*)&Al[nl][l * 8] = make_uint4(lw[0], lw[1], lw[2], lw[3]);
    }
    __syncthreads();

    // ---- phase 2: MFMA 16x128 tile ----
    const int lane = tid & 63;
    const int wid  = tid >> 6;                 // wave -> 32-col strip
    const int rr = lane & 15, kb = lane >> 4;  // rr: row/col in 16-tile, kb: k-block

    const u16* wthp[2]; const u16* wtlp[2];
    #pragma unroll
    for (int nt = 0; nt < 2; ++nt) {
        int c = wid * 32 + nt * 16 + rr;
        wthp[nt] = &wth[(size_t)c * 256];
        wtlp[nt] = &wtl[(size_t)c * 256];
    }
    int srow = node0 + rr;
    if (srow >= n) srow = n - 1;               // clamped; masked at write

    f32x4 acc2[2];
    acc2[0] = (f32x4){0.f, 0.f, 0.f, 0.f};
    acc2[1] = (f32x4){0.f, 0.f, 0.f, 0.f};

    #pragma unroll
    for (int ks = 0; ks < 8; ++ks) {
        const int kfrag = ks * 32 + kb * 8;
        bf16x8 bh0 = *(const bf16x8*)&wthp[0][kfrag];
        bf16x8 bl0 = *(const bf16x8*)&wtlp[0][kfrag];
        bf16x8 bh1 = *(const bf16x8*)&wthp[1][kfrag];
        bf16x8 bl1 = *(const bf16x8*)&wtlp[1][kfrag];
        if (ks < 4) {
            const int ka = ks * 32 + kb * 8;
            bf16x8 ah = *(const bf16x8*)&Ah[rr][ka];
            bf16x8 al = *(const bf16x8*)&Al[rr][ka];
            acc2[0] = __builtin_amdgcn_mfma_f32_16x16x32_bf16(ah, bh0, acc2[0], 0, 0, 0);
            acc2[0] = __builtin_amdgcn_mfma_f32_16x16x32_bf16(al, bh0, acc2[0], 0, 0, 0);
            acc2[0] = __builtin_amdgcn_mfma_f32_16x16x32_bf16(ah, bl0, acc2[0], 0, 0, 0);
            acc2[1] = __builtin_amdgcn_mfma_f32_16x16x32_bf16(ah, bh1, acc2[1], 0, 0, 0);
            acc2[1] = __builtin_amdgcn_mfma_f32_16x16x32_bf16(al, bh1, acc2[1], 0, 0, 0);
            acc2[1] = __builtin_amdgcn_mfma_f32_16x16x32_bf16(ah, bl1, acc2[1], 0, 0, 0);
        } else {
            const int ka = (ks - 4) * 32 + kb * 8;
            bf16x8 ah = *(const bf16x8*)&feat[(size_t)srow * NDIM + ka];
            acc2[0] = __builtin_amdgcn_mfma_f32_16x16x32_bf16(ah, bh0, acc2[0], 0, 0, 0);
            acc2[0] = __builtin_amdgcn_mfma_f32_16x16x32_bf16(ah, bl0, acc2[0], 0, 0, 0);
            acc2[1] = __builtin_amdgcn_mfma_f32_16x16x32_bf16(ah, bh1, acc2[1], 0, 0, 0);
            acc2[1] = __builtin_amdgcn_mfma_f32_16x16x32_bf16(ah, bl1, acc2[1], 0, 0, 0);
        }
    }

    // epilogue: D col = rr, row = kb*4 + reg
    #pragma unroll
    for (int nt = 0; nt < 2; ++nt) {
        int gcol = wid * 32 + nt * 16 + rr;
        float bb = bias[gcol];
        #pragma unroll
        for (int r = 0; r < 4; ++r) {
            int grow = node0 + kb * 4 + r;
            if (grow < n) {
                float v = acc2[nt][r] + bb;
                if (do_relu) v = fmaxf(v, 0.f);
                if (outF) outF[(size_t)grow * NDIM + gcol] = v;
                if (outH) outH[(size_t)grow * NDIM + gcol] = f2bf(v);
            }
        }
    }
}

// ---------------- launch ----------------

extern "C" void kernel_launch(void* const* d_in, const int* in_sizes, int n_in,
                              void* d_out, int out_size, void* d_ws, size_t ws_size,
                              hipStream_t stream) {
    const float* x    = (const float*)d_in[0];
    const int*   ei   = (const int*)d_in[1];
    const float* w1_l = (const float*)d_in[2];
    const float* b1   = (const float*)d_in[3];
    const float* w1_r = (const float*)d_in[4];
    const float* w2_l = (const float*)d_in[5];
    const float* b2   = (const float*)d_in[6];
    const float* w2_r = (const float*)d_in[7];
    const int N = in_sizes[0] / NDIM;
    const int E = in_sizes[1] / 2;
    float* out = (float*)d_out;

    const int NB = (N + BKT_NODES - 1) >> BKT_SHIFT;

    char* ws = (char*)d_ws;
    size_t off = 0;
    auto take = [&](size_t bytes) -> char* {
        char* p = ws + off;
        off += (bytes + 255) & ~(size_t)255;
        return p;
    };
    int* row_beg = (int*)take((size_t)N * 4);
    int* degN    = (int*)take((size_t)N * 4);
    int* gcur    = (int*)take((size_t)NB * 4);
    u32* ebuf    = (u32*)take((size_t)NB * BKT_CAP * 4);
    int* colA    = (int*)take((size_t)NB * BKT_CAP * 4);
    u16* wt1h    = (u16*)take(128 * 256 * 2);
    u16* wt1l    = (u16*)take(128 * 256 * 2);
    u16* wt2h    = (u16*)take(128 * 256 * 2);
    u16* wt2l    = (u16*)take(128 * 256 * 2);
    u16* hh      = (u16*)take((size_t)N * NDIM * 2);
    // xh lives in d_out: free scratch until the layer-2 epilogue overwrites it
    u16* xh      = (u16*)d_out;

    hipMemsetAsync(gcur, 0, (size_t)NB * 4, stream);
    partition_kernel<<<(E + PART_CHUNK - 1) / PART_CHUNK, 256, 0, stream>>>(ei, E, gcur, ebuf);
    bucket_csr_kernel<<<NB, 256, 0, stream>>>(gcur, ebuf, row_beg, degN, colA, N);
    build_wt_kernel<<<128, 256, 0, stream>>>(w1_l, w1_r, wt1h, wt1l);
    build_wt_kernel<<<128, 256, 0, stream>>>(w2_l, w2_r, wt2h, wt2l);
    to_bf16_kernel<<<2048, 256, 0, stream>>>(x, xh, N * NDIM / 4);

    const int gblk = (N + 15) / 16;
    // layer 1: h_hi = bf16(relu([mean(x) | x] @ Wt1 + b1))
    fused_agg_gemm_kernel<<<gblk, 256, 0, stream>>>(xh, row_beg, degN, colA,
                                                    wt1h, wt1l, b1,
                                                    (float*)0, hh, N, 1);
    // layer 2: out = [mean(h) | h] @ Wt2 + b2  (fp32; overwrites xh scratch in d_out)
    fused_agg_gemm_kernel<<<gblk, 256, 0, stream>>>(hh, row_beg, degN, colA,
                                                    wt2h, wt2l, b2,
                                                    out, (u16*)0, N, 0);
}

// Round 9
// 326.437 us; speedup vs baseline: 1.0681x; 1.0681x over previous
//
#include <hip/hip_runtime.h>

#define NDIM 128
#define BKT_SHIFT 9            // 512 nodes per bucket
#define BKT_NODES 512
#define BKT_CAP   12288        // edges capacity per bucket (mean ~8163)
#define PART_CHUNK 4096        // edges per block in partition kernel

typedef unsigned short u16;
typedef unsigned int u32;
typedef __attribute__((ext_vector_type(8))) short bf16x8;
typedef __attribute__((ext_vector_type(4))) float f32x4;

__device__ inline u16 f2bf(float f) {
    u32 u = __float_as_uint(f);
    u += 0x7fffu + ((u >> 16) & 1u);   // RNE
    return (u16)(u >> 16);
}
__device__ inline float bf2f(u16 h) { return __uint_as_float((u32)h << 16); }

// ---------------- bucketed CSR build (unchanged — working) ----------------

__global__ __launch_bounds__(256) void partition_kernel(
    const int* __restrict__ ei, int E,
    int* __restrict__ gcur, u32* __restrict__ ebuf) {
    __shared__ int hcnt[256];
    __shared__ int hbase[256];
    const int tid = threadIdx.x;
    const int base = blockIdx.x * PART_CHUNK;
    hcnt[tid] = 0;
    __syncthreads();

    u32 val[16];
    int bkt[16];
    #pragma unroll
    for (int k = 0; k < 16; ++k) {
        int e = base + k * 256 + tid;
        bkt[k] = -1;
        if (e < E) {
            int src = ei[e];
            int dst = ei[(size_t)E + e];
            int b = dst >> BKT_SHIFT;
            bkt[k] = b;
            val[k] = ((u32)src << BKT_SHIFT) | (u32)(dst & (BKT_NODES - 1));
            atomicAdd(&hcnt[b], 1);
        }
    }
    __syncthreads();
    {
        int c = hcnt[tid];
        if (c > 0) hbase[tid] = atomicAdd(&gcur[tid], c);
        hcnt[tid] = 0;   // reuse as rank counter
    }
    __syncthreads();
    #pragma unroll
    for (int k = 0; k < 16; ++k) {
        if (bkt[k] >= 0) {
            int b = bkt[k];
            int r = atomicAdd(&hcnt[b], 1);
            int off = hbase[b] + r;
            if (off < BKT_CAP)
                ebuf[(size_t)b * BKT_CAP + off] = val[k];
        }
    }
}

__global__ __launch_bounds__(256) void bucket_csr_kernel(
    const int* __restrict__ gcur, const u32* __restrict__ ebuf,
    int* __restrict__ row_beg, int* __restrict__ degN,
    int* __restrict__ col, int n) {
    __shared__ int deg_l[BKT_NODES];
    __shared__ int pre_l[BKT_NODES];
    __shared__ int cur_l[BKT_NODES];
    __shared__ int wsum[4];
    const int tid = threadIdx.x;
    const int lane = tid & 63, wid = tid >> 6;
    const int b = blockIdx.x;
    const int node0 = b << BKT_SHIFT;
    int cnt = gcur[b];
    if (cnt > BKT_CAP) cnt = BKT_CAP;
    const size_t ebase = (size_t)b * BKT_CAP;

    deg_l[tid] = 0; deg_l[tid + 256] = 0;
    cur_l[tid] = 0; cur_l[tid + 256] = 0;
    __syncthreads();

    for (int i = tid; i < cnt; i += 256)
        atomicAdd(&deg_l[ebuf[ebase + i] & (BKT_NODES - 1)], 1);
    __syncthreads();

    int v0 = deg_l[2 * tid], v1 = deg_l[2 * tid + 1];
    int s = v0 + v1, inc = s;
    #pragma unroll
    for (int d = 1; d < 64; d <<= 1) {
        int t = __shfl_up(inc, d, 64);
        if (lane >= d) inc += t;
    }
    if (lane == 63) wsum[wid] = inc;
    __syncthreads();
    int woff = 0;
    for (int w = 0; w < wid; ++w) woff += wsum[w];
    int ex = woff + (inc - s);
    pre_l[2 * tid] = ex;
    pre_l[2 * tid + 1] = ex + v0;
    __syncthreads();

    #pragma unroll
    for (int p = 0; p < 2; ++p) {
        int idx = tid + p * 256;
        int node = node0 + idx;
        if (node < n) {
            row_beg[node] = (int)ebase + pre_l[idx];
            degN[node]    = deg_l[idx];
        }
    }

    for (int i = tid; i < cnt; i += 256) {
        u32 v = ebuf[ebase + i];
        int d = v & (BKT_NODES - 1);
        int r = atomicAdd(&cur_l[d], 1);
        col[ebase + pre_l[d] + r] = (int)(v >> BKT_SHIFT);
    }
}

// ---------------- weight prep: Wt[o][k] split bf16 hi/lo, k = [w_l | w_r] ----------------

__global__ void build_wt_kernel(const float* __restrict__ wl,
                                const float* __restrict__ wr,
                                u16* __restrict__ wth, u16* __restrict__ wtl) {
    int idx = blockIdx.x * blockDim.x + threadIdx.x;
    if (idx >= 128 * 256) return;
    int o = idx >> 8, k = idx & 255;
    float v = (k < 128) ? wl[o * 128 + k] : wr[o * 128 + (k - 128)];
    u16 hi = f2bf(v);
    wth[idx] = hi;
    wtl[idx] = f2bf(v - bf2f(hi));
}

// ---------------- fp32 -> bf16(hi) table ----------------

__global__ __launch_bounds__(256) void to_bf16_kernel(
    const float* __restrict__ in, u16* __restrict__ out, int n4) {
    int stride = gridDim.x * blockDim.x;
    for (int i = blockIdx.x * blockDim.x + threadIdx.x; i < n4; i += stride) {
        float4 v = *(const float4*)&in[(size_t)i * 4];
        ushort4 o;
        o.x = f2bf(v.x); o.y = f2bf(v.y); o.z = f2bf(v.z); o.w = f2bf(v.w);
        *(ushort4*)&out[(size_t)i * 4] = o;
    }
}

// ---------------- mean aggregation: bf16 gather, fp32 accum, split hi/lo out ----------------

__device__ inline void accum8(float acc[8], uint4 u) {
    const u32* p = (const u32*)&u;
    #pragma unroll
    for (int q = 0; q < 4; ++q) {
        u32 w = p[q];
        acc[2 * q]     += __uint_as_float(w << 16);
        acc[2 * q + 1] += __uint_as_float(w & 0xffff0000u);
    }
}

__global__ __launch_bounds__(256) void aggregate_bf16_kernel(
    const u16* __restrict__ feat, const int* __restrict__ row_beg,
    const int* __restrict__ degN, const int* __restrict__ col,
    u16* __restrict__ aggh, u16* __restrict__ aggl, int n) {
    int node = blockIdx.x * 16 + (threadIdx.x >> 4);
    if (node >= n) return;
    int l = threadIdx.x & 15;   // dims [8l, 8l+8)
    int beg = row_beg[node];
    int dg  = degN[node];
    int end = beg + dg;
    float acc[8] = {0.f, 0.f, 0.f, 0.f, 0.f, 0.f, 0.f, 0.f};
    int j = beg;
    for (; j + 4 <= end; j += 4) {
        int s0 = col[j], s1 = col[j + 1], s2 = col[j + 2], s3 = col[j + 3];
        uint4 u0 = *(const uint4*)&feat[(size_t)s0 * NDIM + l * 8];
        uint4 u1 = *(const uint4*)&feat[(size_t)s1 * NDIM + l * 8];
        uint4 u2 = *(const uint4*)&feat[(size_t)s2 * NDIM + l * 8];
        uint4 u3 = *(const uint4*)&feat[(size_t)s3 * NDIM + l * 8];
        accum8(acc, u0); accum8(acc, u1); accum8(acc, u2); accum8(acc, u3);
    }
    for (; j < end; ++j) {
        uint4 u = *(const uint4*)&feat[(size_t)col[j] * NDIM + l * 8];
        accum8(acc, u);
    }
    float inv = (dg > 0) ? 1.0f / (float)dg : 0.f;
    u16 hs[8], ls[8];
    #pragma unroll
    for (int q = 0; q < 8; ++q) {
        float v = acc[q] * inv;
        u16 hi = f2bf(v);
        hs[q] = hi;
        ls[q] = f2bf(v - bf2f(hi));
    }
    *(ushort4*)&aggh[(size_t)node * NDIM + l * 8]     = make_ushort4(hs[0], hs[1], hs[2], hs[3]);
    *(ushort4*)&aggh[(size_t)node * NDIM + l * 8 + 4] = make_ushort4(hs[4], hs[5], hs[6], hs[7]);
    *(ushort4*)&aggl[(size_t)node * NDIM + l * 8]     = make_ushort4(ls[0], ls[1], ls[2], ls[3]);
    *(ushort4*)&aggl[(size_t)node * NDIM + l * 8 + 4] = make_ushort4(ls[4], ls[5], ls[6], ls[7]);
}

// ---------------- MFMA GEMM: out = [agg | xh] @ Wt^T + bias ----------------
// Block 128x128, 4 waves in 2x2, wave tile 64x64 (mt=4, nt=4).
// Depth-1 software pipeline: fragment sets [2] double-buffered; loads of step
// ks+1 are issued before the MFMA cluster of step ks. launch_bounds(256,1)
// frees the register allocator (~210 VGPR) to keep both sets live — R6/R7
// showed the compiler at 56-88 VGPR serializes load-wait-MFMA (MfmaUtil 7-8%).

__global__ __launch_bounds__(256, 1) void gemm_mfma_kernel(
    const u16* __restrict__ aggh, const u16* __restrict__ aggl,
    const u16* __restrict__ xh,
    const u16* __restrict__ wth, const u16* __restrict__ wtl,
    const float* __restrict__ bias,
    float* __restrict__ outF, u16* __restrict__ outH,
    int M, int do_relu) {
    const int tid  = threadIdx.x;
    const int lane = tid & 63;
    const int wid  = tid >> 6;
    const int wr = wid >> 1, wc = wid & 1;     // 2x2 wave grid: 64x64 each
    const int rr = lane & 15, kb = lane >> 4;  // rr: row/col-in-tile, kb: k-block
    const int m0 = blockIdx.x * 128;

    int arow[4];
    #pragma unroll
    for (int mt = 0; mt < 4; ++mt) {
        int r = m0 + wr * 64 + mt * 16 + rr;
        arow[mt] = (r < M) ? r : (M - 1);
    }
    const u16* wthp[4]; const u16* wtlp[4];
    #pragma unroll
    for (int nt = 0; nt < 4; ++nt) {
        int c = wc * 64 + nt * 16 + rr;
        wthp[nt] = &wth[(size_t)c * 256];
        wtlp[nt] = &wtl[(size_t)c * 256];
    }

    f32x4 acc[4][4];
    #pragma unroll
    for (int mt = 0; mt < 4; ++mt)
        #pragma unroll
        for (int nt = 0; nt < 4; ++nt)
            acc[mt][nt] = (f32x4){0.f, 0.f, 0.f, 0.f};

    // double-buffered fragment sets (all indices static after unroll)
    bf16x8 AH[2][4], AL[2][4], BH[2][4], BL[2][4];

    // prefetch ks = 0 (agg side)
    {
        const int kf = kb * 8;
        #pragma unroll
        for (int nt = 0; nt < 4; ++nt) {
            BH[0][nt] = *(const bf16x8*)&wthp[nt][kf];
            BL[0][nt] = *(const bf16x8*)&wtlp[nt][kf];
        }
        #pragma unroll
        for (int mt = 0; mt < 4; ++mt) {
            AH[0][mt] = *(const bf16x8*)&aggh[(size_t)arow[mt] * NDIM + kf];
            AL[0][mt] = *(const bf16x8*)&aggl[(size_t)arow[mt] * NDIM + kf];
        }
    }

    #pragma unroll
    for (int ks = 0; ks < 8; ++ks) {
        const int cur = ks & 1, nxt = cur ^ 1;
        // issue next step's loads first — they fly during this step's MFMAs
        if (ks < 7) {
            const int k2 = ks + 1;
            const int kf = k2 * 32 + kb * 8;
            #pragma unroll
            for (int nt = 0; nt < 4; ++nt) {
                BH[nxt][nt] = *(const bf16x8*)&wthp[nt][kf];
                BL[nxt][nt] = *(const bf16x8*)&wtlp[nt][kf];
            }
            if (k2 < 4) {
                #pragma unroll
                for (int mt = 0; mt < 4; ++mt) {
                    AH[nxt][mt] = *(const bf16x8*)&aggh[(size_t)arow[mt] * NDIM + kf];
                    AL[nxt][mt] = *(const bf16x8*)&aggl[(size_t)arow[mt] * NDIM + kf];
                }
            } else {
                const int ka = (k2 - 4) * 32 + kb * 8;
                #pragma unroll
                for (int mt = 0; mt < 4; ++mt)
                    AH[nxt][mt] = *(const bf16x8*)&xh[(size_t)arow[mt] * NDIM + ka];
            }
        }
        // MFMA cluster for step ks
        if (ks < 4) {
            #pragma unroll
            for (int mt = 0; mt < 4; ++mt)
                #pragma unroll
                for (int nt = 0; nt < 4; ++nt) {
                    acc[mt][nt] = __builtin_amdgcn_mfma_f32_16x16x32_bf16(AH[cur][mt], BH[cur][nt], acc[mt][nt], 0, 0, 0);
                    acc[mt][nt] = __builtin_amdgcn_mfma_f32_16x16x32_bf16(AL[cur][mt], BH[cur][nt], acc[mt][nt], 0, 0, 0);
                    acc[mt][nt] = __builtin_amdgcn_mfma_f32_16x16x32_bf16(AH[cur][mt], BL[cur][nt], acc[mt][nt], 0, 0, 0);
                }
        } else {
            #pragma unroll
            for (int mt = 0; mt < 4; ++mt)
                #pragma unroll
                for (int nt = 0; nt < 4; ++nt) {
                    acc[mt][nt] = __builtin_amdgcn_mfma_f32_16x16x32_bf16(AH[cur][mt], BH[cur][nt], acc[mt][nt], 0, 0, 0);
                    acc[mt][nt] = __builtin_amdgcn_mfma_f32_16x16x32_bf16(AH[cur][mt], BL[cur][nt], acc[mt][nt], 0, 0, 0);
                }
        }
    }

    // epilogue: D col = lane&15 (=rr), row = kb*4 + reg
    #pragma unroll
    for (int nt = 0; nt < 4; ++nt) {
        int gcol = wc * 64 + nt * 16 + rr;
        float bb = bias[gcol];
        #pragma unroll
        for (int mt = 0; mt < 4; ++mt) {
            #pragma unroll
            for (int r = 0; r < 4; ++r) {
                int grow = m0 + wr * 64 + mt * 16 + kb * 4 + r;
                if (grow < M) {
                    float v = acc[mt][nt][r] + bb;
                    if (do_relu) v = fmaxf(v, 0.f);
                    if (outF) outF[(size_t)grow * NDIM + gcol] = v;
                    if (outH) outH[(size_t)grow * NDIM + gcol] = f2bf(v);
                }
            }
        }
    }
}

// ---------------- launch ----------------

extern "C" void kernel_launch(void* const* d_in, const int* in_sizes, int n_in,
                              void* d_out, int out_size, void* d_ws, size_t ws_size,
                              hipStream_t stream) {
    const float* x    = (const float*)d_in[0];
    const int*   ei   = (const int*)d_in[1];
    const float* w1_l = (const float*)d_in[2];
    const float* b1   = (const float*)d_in[3];
    const float* w1_r = (const float*)d_in[4];
    const float* w2_l = (const float*)d_in[5];
    const float* b2   = (const float*)d_in[6];
    const float* w2_r = (const float*)d_in[7];
    const int N = in_sizes[0] / NDIM;
    const int E = in_sizes[1] / 2;
    float* out = (float*)d_out;

    const int NB = (N + BKT_NODES - 1) >> BKT_SHIFT;

    char* ws = (char*)d_ws;
    size_t off = 0;
    auto take = [&](size_t bytes) -> char* {
        char* p = ws + off;
        off += (bytes + 255) & ~(size_t)255;
        return p;
    };
    int* row_beg = (int*)take((size_t)N * 4);
    int* degN    = (int*)take((size_t)N * 4);
    int* gcur    = (int*)take((size_t)NB * 4);
    u32* ebuf    = (u32*)take((size_t)NB * BKT_CAP * 4);
    int* colA    = (int*)take((size_t)NB * BKT_CAP * 4);
    u16* wt1h    = (u16*)take(128 * 256 * 2);
    u16* wt1l    = (u16*)take(128 * 256 * 2);
    u16* wt2h    = (u16*)take(128 * 256 * 2);
    u16* wt2l    = (u16*)take(128 * 256 * 2);
    u16* aggh    = (u16*)take((size_t)N * NDIM * 2);
    u16* aggl    = (u16*)take((size_t)N * NDIM * 2);
    u16* hh      = (u16*)take((size_t)N * NDIM * 2);
    // xh lives in d_out: free scratch until the layer-2 epilogue overwrites it
    u16* xh      = (u16*)d_out;

    hipMemsetAsync(gcur, 0, (size_t)NB * 4, stream);
    partition_kernel<<<(E + PART_CHUNK - 1) / PART_CHUNK, 256, 0, stream>>>(ei, E, gcur, ebuf);
    bucket_csr_kernel<<<NB, 256, 0, stream>>>(gcur, ebuf, row_beg, degN, colA, N);
    build_wt_kernel<<<128, 256, 0, stream>>>(w1_l, w1_r, wt1h, wt1l);
    build_wt_kernel<<<128, 256, 0, stream>>>(w2_l, w2_r, wt2h, wt2l);
    to_bf16_kernel<<<2048, 256, 0, stream>>>(x, xh, N * NDIM / 4);

    const int gblk = (N + 127) / 128;
    // layer 1: h_hi = bf16(relu([mean(x) | x] @ Wt1 + b1))   (no fp32 h)
    aggregate_bf16_kernel<<<(N + 15) / 16, 256, 0, stream>>>(xh, row_beg, degN, colA, aggh, aggl, N);
    gemm_mfma_kernel<<<gblk, 256, 0, stream>>>(aggh, aggl, xh, wt1h, wt1l, b1,
                                               (float*)0, hh, N, 1);
    // layer 2: out = [mean(h) | h] @ Wt2 + b2  (fp32, overwrites xh scratch in d_out)
    aggregate_bf16_kernel<<<(N + 15) / 16, 256, 0, stream>>>(hh, row_beg, degN, colA, aggh, aggl, N);
    gemm_mfma_kernel<<<gblk, 256, 0, stream>>>(aggh, aggl, hh, wt2h, wt2l, b2,
                                               out, (u16*)0, N, 0);
}

// Round 10
// 294.347 us; speedup vs baseline: 1.1846x; 1.1090x over previous
//
#include <hip/hip_runtime.h>

#define NDIM 128
#define BKT_SHIFT 9            // 512 nodes per bucket
#define BKT_NODES 512
#define BKT_CAP   12288        // edges capacity per bucket (mean ~8163)
#define PART_CHUNK 4096        // edges per block in partition kernel

typedef unsigned short u16;
typedef unsigned int u32;
typedef __attribute__((ext_vector_type(8))) short bf16x8;
typedef __attribute__((ext_vector_type(4))) float f32x4;

__device__ inline u16 f2bf(float f) {
    u32 u = __float_as_uint(f);
    u += 0x7fffu + ((u >> 16) & 1u);   // RNE
    return (u16)(u >> 16);
}
__device__ inline float bf2f(u16 h) { return __uint_as_float((u32)h << 16); }

__device__ __forceinline__ void gl_lds16(const void* g, void* l) {
    // async global->LDS, 16B per lane; LDS dest = wave-uniform base + lane*16
    __builtin_amdgcn_global_load_lds(
        (const __attribute__((address_space(1))) void*)g,
        (__attribute__((address_space(3))) void*)l, 16, 0, 0);
}

// ---------------- bucketed CSR build (unchanged — working) ----------------

__global__ __launch_bounds__(256) void partition_kernel(
    const int* __restrict__ ei, int E,
    int* __restrict__ gcur, u32* __restrict__ ebuf) {
    __shared__ int hcnt[256];
    __shared__ int hbase[256];
    const int tid = threadIdx.x;
    const int base = blockIdx.x * PART_CHUNK;
    hcnt[tid] = 0;
    __syncthreads();

    u32 val[16];
    int bkt[16];
    #pragma unroll
    for (int k = 0; k < 16; ++k) {
        int e = base + k * 256 + tid;
        bkt[k] = -1;
        if (e < E) {
            int src = ei[e];
            int dst = ei[(size_t)E + e];
            int b = dst >> BKT_SHIFT;
            bkt[k] = b;
            val[k] = ((u32)src << BKT_SHIFT) | (u32)(dst & (BKT_NODES - 1));
            atomicAdd(&hcnt[b], 1);
        }
    }
    __syncthreads();
    {
        int c = hcnt[tid];
        if (c > 0) hbase[tid] = atomicAdd(&gcur[tid], c);
        hcnt[tid] = 0;   // reuse as rank counter
    }
    __syncthreads();
    #pragma unroll
    for (int k = 0; k < 16; ++k) {
        if (bkt[k] >= 0) {
            int b = bkt[k];
            int r = atomicAdd(&hcnt[b], 1);
            int off = hbase[b] + r;
            if (off < BKT_CAP)
                ebuf[(size_t)b * BKT_CAP + off] = val[k];
        }
    }
}

__global__ __launch_bounds__(256) void bucket_csr_kernel(
    const int* __restrict__ gcur, const u32* __restrict__ ebuf,
    int* __restrict__ row_beg, int* __restrict__ degN,
    int* __restrict__ col, int n) {
    __shared__ int deg_l[BKT_NODES];
    __shared__ int pre_l[BKT_NODES];
    __shared__ int cur_l[BKT_NODES];
    __shared__ int wsum[4];
    const int tid = threadIdx.x;
    const int lane = tid & 63, wid = tid >> 6;
    const int b = blockIdx.x;
    const int node0 = b << BKT_SHIFT;
    int cnt = gcur[b];
    if (cnt > BKT_CAP) cnt = BKT_CAP;
    const size_t ebase = (size_t)b * BKT_CAP;

    deg_l[tid] = 0; deg_l[tid + 256] = 0;
    cur_l[tid] = 0; cur_l[tid + 256] = 0;
    __syncthreads();

    for (int i = tid; i < cnt; i += 256)
        atomicAdd(&deg_l[ebuf[ebase + i] & (BKT_NODES - 1)], 1);
    __syncthreads();

    int v0 = deg_l[2 * tid], v1 = deg_l[2 * tid + 1];
    int s = v0 + v1, inc = s;
    #pragma unroll
    for (int d = 1; d < 64; d <<= 1) {
        int t = __shfl_up(inc, d, 64);
        if (lane >= d) inc += t;
    }
    if (lane == 63) wsum[wid] = inc;
    __syncthreads();
    int woff = 0;
    for (int w = 0; w < wid; ++w) woff += wsum[w];
    int ex = woff + (inc - s);
    pre_l[2 * tid] = ex;
    pre_l[2 * tid + 1] = ex + v0;
    __syncthreads();

    #pragma unroll
    for (int p = 0; p < 2; ++p) {
        int idx = tid + p * 256;
        int node = node0 + idx;
        if (node < n) {
            row_beg[node] = (int)ebase + pre_l[idx];
            degN[node]    = deg_l[idx];
        }
    }

    for (int i = tid; i < cnt; i += 256) {
        u32 v = ebuf[ebase + i];
        int d = v & (BKT_NODES - 1);
        int r = atomicAdd(&cur_l[d], 1);
        col[ebase + pre_l[d] + r] = (int)(v >> BKT_SHIFT);
    }
}

// ---------------- weight prep: Wt[o][k] split bf16 hi/lo, k = [w_l | w_r] ----------------

__global__ void build_wt_kernel(const float* __restrict__ wl,
                                const float* __restrict__ wr,
                                u16* __restrict__ wth, u16* __restrict__ wtl) {
    int idx = blockIdx.x * blockDim.x + threadIdx.x;
    if (idx >= 128 * 256) return;
    int o = idx >> 8, k = idx & 255;
    float v = (k < 128) ? wl[o * 128 + k] : wr[o * 128 + (k - 128)];
    u16 hi = f2bf(v);
    wth[idx] = hi;
    wtl[idx] = f2bf(v - bf2f(hi));
}

// ---------------- fp32 -> bf16(hi) table ----------------

__global__ __launch_bounds__(256) void to_bf16_kernel(
    const float* __restrict__ in, u16* __restrict__ out, int n4) {
    int stride = gridDim.x * blockDim.x;
    for (int i = blockIdx.x * blockDim.x + threadIdx.x; i < n4; i += stride) {
        float4 v = *(const float4*)&in[(size_t)i * 4];
        ushort4 o;
        o.x = f2bf(v.x); o.y = f2bf(v.y); o.z = f2bf(v.z); o.w = f2bf(v.w);
        *(ushort4*)&out[(size_t)i * 4] = o;
    }
}

// ---------------- mean aggregation: bf16 gather, fp32 accum, bf16 out ----------------

__device__ inline void accum8(float acc[8], uint4 u) {
    const u32* p = (const u32*)&u;
    #pragma unroll
    for (int q = 0; q < 4; ++q) {
        u32 w = p[q];
        acc[2 * q]     += __uint_as_float(w << 16);
        acc[2 * q + 1] += __uint_as_float(w & 0xffff0000u);
    }
}

__global__ __launch_bounds__(256) void aggregate_bf16_kernel(
    const u16* __restrict__ feat, const int* __restrict__ row_beg,
    const int* __restrict__ degN, const int* __restrict__ col,
    u16* __restrict__ aggh, int n) {
    int node = blockIdx.x * 16 + (threadIdx.x >> 4);
    if (node >= n) return;
    int l = threadIdx.x & 15;   // dims [8l, 8l+8)
    int beg = row_beg[node];
    int dg  = degN[node];
    int end = beg + dg;
    float acc[8] = {0.f, 0.f, 0.f, 0.f, 0.f, 0.f, 0.f, 0.f};
    int j = beg;
    for (; j + 4 <= end; j += 4) {
        int s0 = col[j], s1 = col[j + 1], s2 = col[j + 2], s3 = col[j + 3];
        uint4 u0 = *(const uint4*)&feat[(size_t)s0 * NDIM + l * 8];
        uint4 u1 = *(const uint4*)&feat[(size_t)s1 * NDIM + l * 8];
        uint4 u2 = *(const uint4*)&feat[(size_t)s2 * NDIM + l * 8];
        uint4 u3 = *(const uint4*)&feat[(size_t)s3 * NDIM + l * 8];
        accum8(acc, u0); accum8(acc, u1); accum8(acc, u2); accum8(acc, u3);
    }
    for (; j < end; ++j) {
        uint4 u = *(const uint4*)&feat[(size_t)col[j] * NDIM + l * 8];
        accum8(acc, u);
    }
    float inv = (dg > 0) ? 1.0f / (float)dg : 0.f;
    u16 hs[8];
    #pragma unroll
    for (int q = 0; q < 8; ++q) hs[q] = f2bf(acc[q] * inv);
    *(ushort4*)&aggh[(size_t)node * NDIM + l * 8]     = make_ushort4(hs[0], hs[1], hs[2], hs[3]);
    *(ushort4*)&aggh[(size_t)node * NDIM + l * 8 + 4] = make_ushort4(hs[4], hs[5], hs[6], hs[7]);
}

// ---------------- MFMA GEMM (m97 structure): out = [agg | self] @ Wt^T + bias ----------------
// 128x128 tile, BK=32, 2x2 waves (64x64 each). LDS double-buffer (2x24KB)
// staged via async global_load_lds (16B/lane). k-major chunk layout
// [kchunk][row]: per-lane GLOBAL source (allowed), lane-linear LDS dest
// (required), and frag ds_read_b128 is 16-lane-contiguous (conflict-free).
// A = single bf16 (agg for ks<4, self for ks>=4); B = W hi + W lo.

__global__ __launch_bounds__(256, 3) void gemm_mfma_kernel(
    const u16* __restrict__ aggh, const u16* __restrict__ selfh,
    const u16* __restrict__ wth, const u16* __restrict__ wtl,
    const float* __restrict__ bias,
    float* __restrict__ outF, u16* __restrict__ outH,
    int M, int do_relu) {
    // buffer layout (16B chunks): [0,512): A  [512,1024): Bh  [1024,1536): Bl
    __shared__ char stageB[2][24576];
    const int tid  = threadIdx.x;
    const int lane = tid & 63;
    const int wid  = tid >> 6;
    const int wr = wid >> 1, wc = wid & 1;
    const int rr = lane & 15, kb = lane >> 4;
    const int m0 = blockIdx.x * 128;

    // per-issue precompute: each wave stages chunks [wid*384, wid*384+383], 6x64
    // chunk c<512: A kc=c>>7,row=c&127 ; c<1024: Bh ; else Bl (ranges 64-aligned
    // within 512-aligned regions -> each issue is single-region, wave-uniform)
    int  aoff[6];        // A: row*256 + kc*16 (add (ks&3)*64 + asrc)
    long boff[6];        // B: byte offset from wth/wtl base (add ks*64)
    int  breg[6];        // 0=A, 1=Bh, 2=Bl
    #pragma unroll
    for (int i = 0; i < 6; ++i) {
        int c = wid * 384 + i * 64 + lane;
        if (c < 512) {
            int kc = c >> 7, row = c & 127;
            int gr = m0 + row; if (gr >= M) gr = M - 1;
            aoff[i] = gr * 256 + kc * 16;
            breg[i] = 0; boff[i] = 0;
        } else if (c < 1024) {
            int cc = c - 512; int kc = cc >> 7, colc = cc & 127;
            boff[i] = (long)colc * 512 + kc * 16;
            breg[i] = 1; aoff[i] = 0;
        } else {
            int cc = c - 1024; int kc = cc >> 7, colc = cc & 127;
            boff[i] = (long)colc * 512 + kc * 16;
            breg[i] = 2; aoff[i] = 0;
        }
    }

    f32x4 acc[4][4];
    #pragma unroll
    for (int mt = 0; mt < 4; ++mt)
        #pragma unroll
        for (int nt = 0; nt < 4; ++nt)
            acc[mt][nt] = (f32x4){0.f, 0.f, 0.f, 0.f};

    auto stage_step = [&](int buf, int ks) {
        const char* asrc = (const char*)((ks < 4) ? aggh : selfh) + (ks & 3) * 64;
        const char* bh = (const char*)wth + ks * 64;
        const char* bl = (const char*)wtl + ks * 64;
        #pragma unroll
        for (int i = 0; i < 6; ++i) {
            const char* g = (breg[i] == 0) ? (asrc + aoff[i])
                          : (breg[i] == 1) ? (bh + boff[i]) : (bl + boff[i]);
            char* l = &stageB[buf][(wid * 384 + i * 64) * 16];
            gl_lds16(g, l);
        }
    };

    stage_step(0, 0);
    __syncthreads();                      // drain vmcnt (compiler-inserted) + barrier

    int cur = 0;
    #pragma unroll
    for (int ks = 0; ks < 8; ++ks) {
        if (ks < 7) stage_step(cur ^ 1, ks + 1);   // async; flies under MFMAs
        const char* sb = stageB[cur];
        bf16x8 ah[4], bh[4], bl[4];
        #pragma unroll
        for (int mt = 0; mt < 4; ++mt) {
            int row = wr * 64 + mt * 16 + rr;
            ah[mt] = *(const bf16x8*)(sb + kb * 2048 + row * 16);
        }
        #pragma unroll
        for (int nt = 0; nt < 4; ++nt) {
            int colc = wc * 64 + nt * 16 + rr;
            bh[nt] = *(const bf16x8*)(sb + 8192  + kb * 2048 + colc * 16);
            bl[nt] = *(const bf16x8*)(sb + 16384 + kb * 2048 + colc * 16);
        }
        #pragma unroll
        for (int mt = 0; mt < 4; ++mt)
            #pragma unroll
            for (int nt = 0; nt < 4; ++nt) {
                acc[mt][nt] = __builtin_amdgcn_mfma_f32_16x16x32_bf16(ah[mt], bh[nt], acc[mt][nt], 0, 0, 0);
                acc[mt][nt] = __builtin_amdgcn_mfma_f32_16x16x32_bf16(ah[mt], bl[nt], acc[mt][nt], 0, 0, 0);
            }
        __syncthreads();                  // reads of cur done; stage(cur^1) drained
        cur ^= 1;
    }

    // epilogue: D col = rr, row = kb*4 + reg (m89/m91 layout)
    #pragma unroll
    for (int nt = 0; nt < 4; ++nt) {
        int gcol = wc * 64 + nt * 16 + rr;
        float bb = bias[gcol];
        #pragma unroll
        for (int mt = 0; mt < 4; ++mt) {
            #pragma unroll
            for (int r = 0; r < 4; ++r) {
                int grow = m0 + wr * 64 + mt * 16 + kb * 4 + r;
                if (grow < M) {
                    float v = acc[mt][nt][r] + bb;
                    if (do_relu) v = fmaxf(v, 0.f);
                    if (outF) outF[(size_t)grow * NDIM + gcol] = v;
                    if (outH) outH[(size_t)grow * NDIM + gcol] = f2bf(v);
                }
            }
        }
    }
}

// ---------------- launch ----------------

extern "C" void kernel_launch(void* const* d_in, const int* in_sizes, int n_in,
                              void* d_out, int out_size, void* d_ws, size_t ws_size,
                              hipStream_t stream) {
    const float* x    = (const float*)d_in[0];
    const int*   ei   = (const int*)d_in[1];
    const float* w1_l = (const float*)d_in[2];
    const float* b1   = (const float*)d_in[3];
    const float* w1_r = (const float*)d_in[4];
    const float* w2_l = (const float*)d_in[5];
    const float* b2   = (const float*)d_in[6];
    const float* w2_r = (const float*)d_in[7];
    const int N = in_sizes[0] / NDIM;
    const int E = in_sizes[1] / 2;
    float* out = (float*)d_out;

    const int NB = (N + BKT_NODES - 1) >> BKT_SHIFT;

    char* ws = (char*)d_ws;
    size_t off = 0;
    auto take = [&](size_t bytes) -> char* {
        char* p = ws + off;
        off += (bytes + 255) & ~(size_t)255;
        return p;
    };
    int* row_beg = (int*)take((size_t)N * 4);
    int* degN    = (int*)take((size_t)N * 4);
    int* gcur    = (int*)take((size_t)NB * 4);
    u32* ebuf    = (u32*)take((size_t)NB * BKT_CAP * 4);
    int* colA    = (int*)take((size_t)NB * BKT_CAP * 4);
    u16* wt1h    = (u16*)take(128 * 256 * 2);
    u16* wt1l    = (u16*)take(128 * 256 * 2);
    u16* wt2h    = (u16*)take(128 * 256 * 2);
    u16* wt2l    = (u16*)take(128 * 256 * 2);
    u16* aggh    = (u16*)take((size_t)N * NDIM * 2);
    u16* hh      = (u16*)take((size_t)N * NDIM * 2);
    // xh lives in d_out: free scratch until the layer-2 epilogue overwrites it
    u16* xh      = (u16*)d_out;

    hipMemsetAsync(gcur, 0, (size_t)NB * 4, stream);
    partition_kernel<<<(E + PART_CHUNK - 1) / PART_CHUNK, 256, 0, stream>>>(ei, E, gcur, ebuf);
    bucket_csr_kernel<<<NB, 256, 0, stream>>>(gcur, ebuf, row_beg, degN, colA, N);
    build_wt_kernel<<<128, 256, 0, stream>>>(w1_l, w1_r, wt1h, wt1l);
    build_wt_kernel<<<128, 256, 0, stream>>>(w2_l, w2_r, wt2h, wt2l);
    to_bf16_kernel<<<2048, 256, 0, stream>>>(x, xh, N * NDIM / 4);

    const int gblk = (N + 127) / 128;
    // layer 1: h = bf16(relu([mean(x) | x] @ Wt1 + b1))
    aggregate_bf16_kernel<<<(N + 15) / 16, 256, 0, stream>>>(xh, row_beg, degN, colA, aggh, N);
    gemm_mfma_kernel<<<gblk, 256, 0, stream>>>(aggh, xh, wt1h, wt1l, b1,
                                               (float*)0, hh, N, 1);
    // layer 2: out = [mean(h) | h] @ Wt2 + b2
    aggregate_bf16_kernel<<<(N + 15) / 16, 256, 0, stream>>>(hh, row_beg, degN, colA, aggh, N);
    gemm_mfma_kernel<<<gblk, 256, 0, stream>>>(aggh, hh, wt2h, wt2l, b2,
                                               out, (u16*)0, N, 0);
}

// Round 11
// 254.118 us; speedup vs baseline: 1.3721x; 1.1583x over previous
//
#include <hip/hip_runtime.h>

#define NDIM 128
#define BKT_SHIFT 9            // 512 nodes per bucket
#define BKT_NODES 512
#define BKT_CAP   12288        // edges capacity per bucket (mean ~8163)
#define PART_CHUNK 4096        // edges per block in partition kernel

typedef unsigned short u16;
typedef unsigned int u32;
typedef __attribute__((ext_vector_type(8))) short bf16x8;
typedef __attribute__((ext_vector_type(4))) float f32x4;

__device__ inline u16 f2bf(float f) {
    u32 u = __float_as_uint(f);
    u += 0x7fffu + ((u >> 16) & 1u);   // RNE
    return (u16)(u >> 16);
}
__device__ inline float bf2f(u16 h) { return __uint_as_float((u32)h << 16); }

// ---------------- bucketed CSR build (unchanged — working) ----------------

__global__ __launch_bounds__(256) void partition_kernel(
    const int* __restrict__ ei, int E,
    int* __restrict__ gcur, u32* __restrict__ ebuf) {
    __shared__ int hcnt[256];
    __shared__ int hbase[256];
    const int tid = threadIdx.x;
    const int base = blockIdx.x * PART_CHUNK;
    hcnt[tid] = 0;
    __syncthreads();

    u32 val[16];
    int bkt[16];
    #pragma unroll
    for (int k = 0; k < 16; ++k) {
        int e = base + k * 256 + tid;
        bkt[k] = -1;
        if (e < E) {
            int src = ei[e];
            int dst = ei[(size_t)E + e];
            int b = dst >> BKT_SHIFT;
            bkt[k] = b;
            val[k] = ((u32)src << BKT_SHIFT) | (u32)(dst & (BKT_NODES - 1));
            atomicAdd(&hcnt[b], 1);
        }
    }
    __syncthreads();
    {
        int c = hcnt[tid];
        if (c > 0) hbase[tid] = atomicAdd(&gcur[tid], c);
        hcnt[tid] = 0;   // reuse as rank counter
    }
    __syncthreads();
    #pragma unroll
    for (int k = 0; k < 16; ++k) {
        if (bkt[k] >= 0) {
            int b = bkt[k];
            int r = atomicAdd(&hcnt[b], 1);
            int off = hbase[b] + r;
            if (off < BKT_CAP)
                ebuf[(size_t)b * BKT_CAP + off] = val[k];
        }
    }
}

__global__ __launch_bounds__(256) void bucket_csr_kernel(
    const int* __restrict__ gcur, const u32* __restrict__ ebuf,
    int* __restrict__ row_beg, int* __restrict__ degN,
    int* __restrict__ col, int n) {
    __shared__ int deg_l[BKT_NODES];
    __shared__ int pre_l[BKT_NODES];
    __shared__ int cur_l[BKT_NODES];
    __shared__ int wsum[4];
    const int tid = threadIdx.x;
    const int lane = tid & 63, wid = tid >> 6;
    const int b = blockIdx.x;
    const int node0 = b << BKT_SHIFT;
    int cnt = gcur[b];
    if (cnt > BKT_CAP) cnt = BKT_CAP;
    const size_t ebase = (size_t)b * BKT_CAP;

    deg_l[tid] = 0; deg_l[tid + 256] = 0;
    cur_l[tid] = 0; cur_l[tid + 256] = 0;
    __syncthreads();

    for (int i = tid; i < cnt; i += 256)
        atomicAdd(&deg_l[ebuf[ebase + i] & (BKT_NODES - 1)], 1);
    __syncthreads();

    int v0 = deg_l[2 * tid], v1 = deg_l[2 * tid + 1];
    int s = v0 + v1, inc = s;
    #pragma unroll
    for (int d = 1; d < 64; d <<= 1) {
        int t = __shfl_up(inc, d, 64);
        if (lane >= d) inc += t;
    }
    if (lane == 63) wsum[wid] = inc;
    __syncthreads();
    int woff = 0;
    for (int w = 0; w < wid; ++w) woff += wsum[w];
    int ex = woff + (inc - s);
    pre_l[2 * tid] = ex;
    pre_l[2 * tid + 1] = ex + v0;
    __syncthreads();

    #pragma unroll
    for (int p = 0; p < 2; ++p) {
        int idx = tid + p * 256;
        int node = node0 + idx;
        if (node < n) {
            row_beg[node] = (int)ebase + pre_l[idx];
            degN[node]    = deg_l[idx];
        }
    }

    for (int i = tid; i < cnt; i += 256) {
        u32 v = ebuf[ebase + i];
        int d = v & (BKT_NODES - 1);
        int r = atomicAdd(&cur_l[d], 1);
        col[ebase + pre_l[d] + r] = (int)(v >> BKT_SHIFT);
    }
}

// ---------------- weight prep: Wt[o][k] split bf16 hi/lo, k = [w_l | w_r] ----------------

__global__ void build_wt_kernel(const float* __restrict__ wl,
                                const float* __restrict__ wr,
                                u16* __restrict__ wth, u16* __restrict__ wtl) {
    int idx = blockIdx.x * blockDim.x + threadIdx.x;
    if (idx >= 128 * 256) return;
    int o = idx >> 8, k = idx & 255;
    float v = (k < 128) ? wl[o * 128 + k] : wr[o * 128 + (k - 128)];
    u16 hi = f2bf(v);
    wth[idx] = hi;
    wtl[idx] = f2bf(v - bf2f(hi));
}

// ---------------- fp32 -> bf16(hi) table ----------------

__global__ __launch_bounds__(256) void to_bf16_kernel(
    const float* __restrict__ in, u16* __restrict__ out, int n4) {
    int stride = gridDim.x * blockDim.x;
    for (int i = blockIdx.x * blockDim.x + threadIdx.x; i < n4; i += stride) {
        float4 v = *(const float4*)&in[(size_t)i * 4];
        ushort4 o;
        o.x = f2bf(v.x); o.y = f2bf(v.y); o.z = f2bf(v.z); o.w = f2bf(v.w);
        *(ushort4*)&out[(size_t)i * 4] = o;
    }
}

// ---------------- mean aggregation: bf16 gather, fp32 accum, bf16 out ----------------

__device__ inline void accum8(float acc[8], uint4 u) {
    const u32* p = (const u32*)&u;
    #pragma unroll
    for (int q = 0; q < 4; ++q) {
        u32 w = p[q];
        acc[2 * q]     += __uint_as_float(w << 16);
        acc[2 * q + 1] += __uint_as_float(w & 0xffff0000u);
    }
}

__global__ __launch_bounds__(256) void aggregate_bf16_kernel(
    const u16* __restrict__ feat, const int* __restrict__ row_beg,
    const int* __restrict__ degN, const int* __restrict__ col,
    u16* __restrict__ aggh, int n) {
    int node = blockIdx.x * 16 + (threadIdx.x >> 4);
    if (node >= n) return;
    int l = threadIdx.x & 15;   // dims [8l, 8l+8)
    int beg = row_beg[node];
    int dg  = degN[node];
    int end = beg + dg;
    float acc[8] = {0.f, 0.f, 0.f, 0.f, 0.f, 0.f, 0.f, 0.f};
    int j = beg;
    for (; j + 4 <= end; j += 4) {
        int s0 = col[j], s1 = col[j + 1], s2 = col[j + 2], s3 = col[j + 3];
        uint4 u0 = *(const uint4*)&feat[(size_t)s0 * NDIM + l * 8];
        uint4 u1 = *(const uint4*)&feat[(size_t)s1 * NDIM + l * 8];
        uint4 u2 = *(const uint4*)&feat[(size_t)s2 * NDIM + l * 8];
        uint4 u3 = *(const uint4*)&feat[(size_t)s3 * NDIM + l * 8];
        accum8(acc, u0); accum8(acc, u1); accum8(acc, u2); accum8(acc, u3);
    }
    for (; j < end; ++j) {
        uint4 u = *(const uint4*)&feat[(size_t)col[j] * NDIM + l * 8];
        accum8(acc, u);
    }
    float inv = (dg > 0) ? 1.0f / (float)dg : 0.f;
    u16 hs[8];
    #pragma unroll
    for (int q = 0; q < 8; ++q) hs[q] = f2bf(acc[q] * inv);
    *(ushort4*)&aggh[(size_t)node * NDIM + l * 8]     = make_ushort4(hs[0], hs[1], hs[2], hs[3]);
    *(ushort4*)&aggh[(size_t)node * NDIM + l * 8 + 4] = make_ushort4(hs[4], hs[5], hs[6], hs[7]);
}

// ---------------- B-stationary MFMA GEMM: out = [agg | self] @ Wt^T + bias ----------------
// Each wave owns a 32-col strip and holds ALL its W fragments (hi+lo, K=256)
// in registers: 32 x bf16x8 = 128 VGPR, loop-invariant -> cannot be demoted
// (R9's reg-dbuf was foldable; this isn't). Waves grid-stride 32-row tiles:
// 16 independent dwordx4 A-frag loads direct from global, 64 MFMA, store.
// No LDS, no barriers, no cross-wave coupling. 512 blocks x 4 waves cover
// 3125 tiles (~6 tiles/wave, B loaded once per wave).

__global__ __launch_bounds__(256, 2) void gemm_bstat_kernel(
    const u16* __restrict__ aggh, const u16* __restrict__ selfh,
    const u16* __restrict__ wth, const u16* __restrict__ wtl,
    const float* __restrict__ bias,
    float* __restrict__ outF, u16* __restrict__ outH,
    int M, int do_relu) {
    const int lane = threadIdx.x & 63;
    const int wid  = threadIdx.x >> 6;        // col strip: cols [wid*32, wid*32+32)
    const int rr = lane & 15, kb = lane >> 4;
    const int c0 = wid * 32;
    const int ntiles = (M + 31) / 32;

    // ---- load all B fragments once (loop-invariant registers) ----
    bf16x8 BH[2][8], BL[2][8];
    #pragma unroll
    for (int nt = 0; nt < 2; ++nt) {
        const u16* bh = &wth[(size_t)(c0 + nt * 16 + rr) * 256];
        const u16* bl = &wtl[(size_t)(c0 + nt * 16 + rr) * 256];
        #pragma unroll
        for (int ks = 0; ks < 8; ++ks) {
            BH[nt][ks] = *(const bf16x8*)&bh[ks * 32 + kb * 8];
            BL[nt][ks] = *(const bf16x8*)&bl[ks * 32 + kb * 8];
        }
    }
    const float bb0 = bias[c0 + rr];
    const float bb1 = bias[c0 + 16 + rr];

    for (int t = blockIdx.x; t < ntiles; t += gridDim.x) {
        const int r0 = t * 32;
        // ---- 16 independent A-frag loads (2 row sub-tiles x 8 k-chunks) ----
        bf16x8 A[2][8];
        #pragma unroll
        for (int mt = 0; mt < 2; ++mt) {
            int row = r0 + mt * 16 + rr;
            if (row >= M) row = M - 1;
            const u16* ag = &aggh[(size_t)row * NDIM];
            const u16* sf = &selfh[(size_t)row * NDIM];
            #pragma unroll
            for (int ks = 0; ks < 4; ++ks) A[mt][ks]     = *(const bf16x8*)&ag[ks * 32 + kb * 8];
            #pragma unroll
            for (int ks = 0; ks < 4; ++ks) A[mt][4 + ks] = *(const bf16x8*)&sf[ks * 32 + kb * 8];
        }
        // ---- 64 MFMA (4 independent acc chains) ----
        f32x4 acc[2][2];
        #pragma unroll
        for (int mt = 0; mt < 2; ++mt)
            #pragma unroll
            for (int nt = 0; nt < 2; ++nt)
                acc[mt][nt] = (f32x4){0.f, 0.f, 0.f, 0.f};
        #pragma unroll
        for (int ks = 0; ks < 8; ++ks)
            #pragma unroll
            for (int mt = 0; mt < 2; ++mt)
                #pragma unroll
                for (int nt = 0; nt < 2; ++nt) {
                    acc[mt][nt] = __builtin_amdgcn_mfma_f32_16x16x32_bf16(A[mt][ks], BH[nt][ks], acc[mt][nt], 0, 0, 0);
                    acc[mt][nt] = __builtin_amdgcn_mfma_f32_16x16x32_bf16(A[mt][ks], BL[nt][ks], acc[mt][nt], 0, 0, 0);
                }
        // ---- epilogue: D col = rr, row = kb*4 + r ----
        #pragma unroll
        for (int mt = 0; mt < 2; ++mt) {
            #pragma unroll
            for (int r = 0; r < 4; ++r) {
                int grow = r0 + mt * 16 + kb * 4 + r;
                if (grow < M) {
                    float v0 = acc[mt][0][r] + bb0;
                    float v1 = acc[mt][1][r] + bb1;
                    if (do_relu) { v0 = fmaxf(v0, 0.f); v1 = fmaxf(v1, 0.f); }
                    if (outF) {
                        outF[(size_t)grow * NDIM + c0 + rr]      = v0;
                        outF[(size_t)grow * NDIM + c0 + 16 + rr] = v1;
                    }
                    if (outH) {
                        outH[(size_t)grow * NDIM + c0 + rr]      = f2bf(v0);
                        outH[(size_t)grow * NDIM + c0 + 16 + rr] = f2bf(v1);
                    }
                }
            }
        }
    }
}

// ---------------- launch ----------------

extern "C" void kernel_launch(void* const* d_in, const int* in_sizes, int n_in,
                              void* d_out, int out_size, void* d_ws, size_t ws_size,
                              hipStream_t stream) {
    const float* x    = (const float*)d_in[0];
    const int*   ei   = (const int*)d_in[1];
    const float* w1_l = (const float*)d_in[2];
    const float* b1   = (const float*)d_in[3];
    const float* w1_r = (const float*)d_in[4];
    const float* w2_l = (const float*)d_in[5];
    const float* b2   = (const float*)d_in[6];
    const float* w2_r = (const float*)d_in[7];
    const int N = in_sizes[0] / NDIM;
    const int E = in_sizes[1] / 2;
    float* out = (float*)d_out;

    const int NB = (N + BKT_NODES - 1) >> BKT_SHIFT;

    char* ws = (char*)d_ws;
    size_t off = 0;
    auto take = [&](size_t bytes) -> char* {
        char* p = ws + off;
        off += (bytes + 255) & ~(size_t)255;
        return p;
    };
    int* row_beg = (int*)take((size_t)N * 4);
    int* degN    = (int*)take((size_t)N * 4);
    int* gcur    = (int*)take((size_t)NB * 4);
    u32* ebuf    = (u32*)take((size_t)NB * BKT_CAP * 4);
    int* colA    = (int*)take((size_t)NB * BKT_CAP * 4);
    u16* wt1h    = (u16*)take(128 * 256 * 2);
    u16* wt1l    = (u16*)take(128 * 256 * 2);
    u16* wt2h    = (u16*)take(128 * 256 * 2);
    u16* wt2l    = (u16*)take(128 * 256 * 2);
    u16* aggh    = (u16*)take((size_t)N * NDIM * 2);
    u16* hh      = (u16*)take((size_t)N * NDIM * 2);
    // xh lives in d_out: free scratch until the layer-2 epilogue overwrites it
    u16* xh      = (u16*)d_out;

    hipMemsetAsync(gcur, 0, (size_t)NB * 4, stream);
    partition_kernel<<<(E + PART_CHUNK - 1) / PART_CHUNK, 256, 0, stream>>>(ei, E, gcur, ebuf);
    bucket_csr_kernel<<<NB, 256, 0, stream>>>(gcur, ebuf, row_beg, degN, colA, N);
    build_wt_kernel<<<128, 256, 0, stream>>>(w1_l, w1_r, wt1h, wt1l);
    build_wt_kernel<<<128, 256, 0, stream>>>(w2_l, w2_r, wt2h, wt2l);
    to_bf16_kernel<<<2048, 256, 0, stream>>>(x, xh, N * NDIM / 4);

    const int gblk = 512;   // 2048 waves grid-stride 3125 row-tiles; B loaded once/wave
    // layer 1: h = bf16(relu([mean(x) | x] @ Wt1 + b1))
    aggregate_bf16_kernel<<<(N + 15) / 16, 256, 0, stream>>>(xh, row_beg, degN, colA, aggh, N);
    gemm_bstat_kernel<<<gblk, 256, 0, stream>>>(aggh, xh, wt1h, wt1l, b1,
                                                (float*)0, hh, N, 1);
    // layer 2: out = [mean(h) | h] @ Wt2 + b2
    aggregate_bf16_kernel<<<(N + 15) / 16, 256, 0, stream>>>(hh, row_beg, degN, colA, aggh, N);
    gemm_bstat_kernel<<<gblk, 256, 0, stream>>>(aggh, hh, wt2h, wt2l, b2,
                                                out, (u16*)0, N, 0);
}